// Round 9
// baseline (71.305 us; speedup 1.0000x reference)
//
#include <hip/hip_runtime.h>
#include <hip/hip_bf16.h>
#include <math.h>

#define B_  4096u
#define N_  8192
#define D_  128
#define M_  8190u          // negatives per logits row = 2B-2
#define SB_ 25159680u      // S_B = B*(2B-2) - B*(B-1)/2
#define NT2_ 1056          // upper-tri 128x256 tiles
#define NBLK 528           // persistent blocks, 2 tiles each

#define AS1 __attribute__((address_space(1)))
#define AS3 __attribute__((address_space(3)))

typedef __attribute__((ext_vector_type(8))) short bf16x8;
typedef __attribute__((ext_vector_type(4))) float f32x4;
typedef __attribute__((ext_vector_type(4))) short short4v;

static __device__ __forceinline__ short f2b(float x) {
  __hip_bfloat16 h = __float2bfloat16(x);
  union { __hip_bfloat16 h; short s; } u; u.h = h; return u.s;
}
// cumulative flat-count of strict-upper (minus positives) elements before row i
static __device__ __forceinline__ unsigned rowS(unsigned i) {
  if (i <= B_) return i * (2u * B_ - 2u) - (i * (i - 1u)) / 2u;
  unsigned d = i - B_;
  return SB_ + d * (B_ - 1u) - (d * (d - 1u)) / 2u;
}
// cumulative tile count before row-panel m (128-row panels, 256-col tiles)
static __device__ __forceinline__ int tile0(int m) {
  return 32 * m - (m * m - 2 * m + (m & 1)) / 4;
}
// 16-lane DPP row_ror rotation reduce: every lane of each 16-group ends with
// the group sum. VALU-rate, no LDS pipe. (validated R7/R8)
template <int CTRL>
static __device__ __forceinline__ float dpp_add(float x) {
  union { float f; int i; } u, r;
  u.f = x;
  r.i = __builtin_amdgcn_mov_dpp(u.i, CTRL, 0xF, 0xF, 0);
  return x + r.f;
}
static __device__ __forceinline__ float rsum16(float x) {
  x = dpp_add<0x121>(x);   // row_ror:1
  x = dpp_add<0x122>(x);   // row_ror:2
  x = dpp_add<0x124>(x);   // row_ror:4
  x = dpp_add<0x128>(x);   // row_ror:8
  return x;
}

// ---------------------------------------------------------------------------
// Kernel A: normalize rows of reps=[zjs;zis] -> bf16 nb[row][k].
// Block 0 zeroes E buckets + completion counter (replay-safe).
// ---------------------------------------------------------------------------
__global__ __launch_bounds__(256) void nt_norm(
    const float* __restrict__ zis, const float* __restrict__ zjs,
    short* __restrict__ nb, unsigned* __restrict__ zbase) {
  const int t   = threadIdx.x;
  const int row = blockIdx.x * 8 + (t >> 5);
  const int c   = t & 31;
  const float* src = (row < (int)B_) ? (zjs + (size_t)row * D_)
                                     : (zis + (size_t)(row - (int)B_) * D_);
  float4 v = *(const float4*)(src + c * 4);
  float s = v.x * v.x + v.y * v.y + v.z * v.z + v.w * v.w;
  #pragma unroll
  for (int m = 16; m >= 1; m >>= 1) s += __shfl_xor(s, m, 32);
  float rn = 1.0f / fmaxf(sqrtf(s), 1e-8f);
  short4v o;
  o[0] = f2b(v.x * rn); o[1] = f2b(v.y * rn);
  o[2] = f2b(v.z * rn); o[3] = f2b(v.w * rn);
  *(short4v*)(nb + (size_t)row * D_ + c * 4) = o;

  if (blockIdx.x == 0) {
    // E (4112 f32) + counter (1 u32), contiguous
    for (int r = t; r < 4128; r += 256) zbase[r] = 0u;
  }
}

// ---------------------------------------------------------------------------
// Kernel B: PERSISTENT upper-tri Gram. 528 blocks x 2 consecutive 128x256
// tiles, 8 waves (2x4). Continuous 8-step pipeline (step = tile*4 + phase):
// vmcnt(0) -> s_barrier -> STAGE(step+1) -> ds_read+16 MFMA; the pipeline
// never drains at the tile boundary. Tile epilogue (inline thresholds, DPP
// reduce) uses raw lgkmcnt(0)+s_barrier so the next tile's prefetch stays
// in flight beneath it. No atomics.
// ---------------------------------------------------------------------------
__global__ __launch_bounds__(512, 4) void nt_gemm(
    const short* __restrict__ nb, float2* __restrict__ part,
    float* __restrict__ posl) {
  const int tb0 = (int)blockIdx.x * 2;
  // decode tile tb0 -> (bi2, bj2)
  int bi2 = (int)(2.0f * (32.0f - sqrtf(fmaxf(0.f, 1024.0f - (float)tb0))));
  if (bi2 > 63) bi2 = 63;
  while (bi2 > 0 && tb0 < tile0(bi2)) --bi2;
  while (tb0 >= tile0(bi2 + 1)) ++bi2;
  int bj2 = (bi2 >> 1) + (tb0 - tile0(bi2));
  // consecutive tile tb0+1
  int bi2b = bi2, bj2b = bj2 + 1;
  if (bj2b >= 32) { bi2b = bi2 + 1; bj2b = bi2b >> 1; }

  __shared__ short As[2][128 * 32];     // 2 x 8KB
  __shared__ short Bs[2][256 * 32];     // 2 x 16KB
  __shared__ float2 red2[4][128];       // 4KB          total 52KB

  const int t    = threadIdx.x;
  const int lane = t & 63, wave = t >> 6;
  const int li   = lane & 15, hi = lane >> 4;
  const int wr   = wave >> 2, wc = wave & 3;   // 2x4 wave grid
  const int i0a  = bi2 * 128,  j0a = bj2 * 256;
  const int i0b  = bi2b * 128, j0b = bj2b * 256;

  const short* gA0 = nb + (size_t)i0a * D_;
  const short* gB0 = nb + (size_t)j0a * D_;
  const short* gA1 = nb + (size_t)i0b * D_;
  const short* gB1 = nb + (size_t)j0b * D_;

#define STAGE(gAp, gBp, ko, buf) do {                                         \
    { int e_ = t; int r_ = e_ >> 2, sl_ = e_ & 3, sg_ = sl_ ^ ((r_ >> 1) & 3);\
      __builtin_amdgcn_global_load_lds(                                       \
          (const AS1 void*)((gAp) + (size_t)r_ * D_ + (ko) + sg_ * 8),        \
          (AS3 void*)(&As[buf][e_ * 8]), 16, 0, 0); }                         \
    _Pragma("unroll")                                                         \
    for (int it_ = 0; it_ < 2; ++it_) {                                       \
      int e_ = it_ * 512 + t;                                                 \
      int r_ = e_ >> 2, sl_ = e_ & 3, sg_ = sl_ ^ ((r_ >> 1) & 3);            \
      __builtin_amdgcn_global_load_lds(                                       \
          (const AS1 void*)((gBp) + (size_t)r_ * D_ + (ko) + sg_ * 8),        \
          (AS3 void*)(&Bs[buf][e_ * 8]), 16, 0, 0); }                         \
  } while (0)

  STAGE(gA0, gB0, 0, 0);   // prologue: tile0 phase0 into buffer 0

  f32x4 acc[4][4];
  #pragma unroll
  for (int m = 0; m < 4; ++m)
    #pragma unroll
    for (int n = 0; n < 4; ++n) acc[m][n] = (f32x4){0.f, 0.f, 0.f, 0.f};

  const int sw = hi ^ ((li >> 1) & 3);   // swizzled 16B slot for ds_read

  #pragma unroll
  for (int s = 0; s < 8; ++s) {          // step = tile*4 + phase
    // loads for buf (s&1) were issued a full step ago -> near-zero wait
    asm volatile("s_waitcnt vmcnt(0)" ::: "memory");
    __builtin_amdgcn_s_barrier();
    __builtin_amdgcn_sched_barrier(0);

    if (s < 7) {
      const short* gAn = ((s + 1) >> 2) ? gA1 : gA0;
      const short* gBn = ((s + 1) >> 2) ? gB1 : gB0;
      STAGE(gAn, gBn, ((s + 1) & 3) * 32, (s + 1) & 1);
    }

    const int cb = s & 1;
    bf16x8 af[4], bfr[4];
    #pragma unroll
    for (int m = 0; m < 4; ++m)
      af[m] = *(const bf16x8*)(&As[cb][(wr * 64 + m * 16 + li) * 32 + sw * 8]);
    #pragma unroll
    for (int n = 0; n < 4; ++n)
      bfr[n] = *(const bf16x8*)(&Bs[cb][(wc * 64 + n * 16 + li) * 32 + sw * 8]);
    #pragma unroll
    for (int m = 0; m < 4; ++m)
      #pragma unroll
      for (int n = 0; n < 4; ++n)
        acc[m][n] = __builtin_amdgcn_mfma_f32_16x16x32_bf16(
            af[m], bfr[n], acc[m][n], 0, 0, 0);

    if ((s & 3) == 3) {
      // ---- tile epilogue (tile index tt = s>>2, compile-time) ----
      const int  ti0  = (s >> 2) ? i0b : i0a;
      const int  tj0  = (s >> 2) ? j0b : j0a;
      const int  tbi2 = (s >> 2) ? bi2b : bi2;
      const int  tbj2 = (s >> 2) ? bj2b : bj2;
      const int  ttb  = tb0 + (s >> 2);
      const int  jlo_t = tbi2 >> 1;
      const bool isdiag = (tbj2 == jlo_t);
      const bool ispost = (tbj2 == jlo_t + 16);
      const bool special = isdiag | ispost;
      const unsigned jw0 = (unsigned)(tj0 + wc * 64);

      #pragma unroll
      for (int m = 0; m < 4; ++m) {
        #pragma unroll
        for (int rg = 0; rg < 4; ++rg) {
          const unsigned i = (unsigned)(ti0 + wr * 64 + m * 16 + hi * 4 + rg);
          const unsigned S = rowS(i);
          unsigned T = (S / M_ + 1u) * M_ - S + i + 1u;  // const-div magic mul
          T += ((i < B_) && (T > i + B_)) ? 1u : 0u;
          float r0, r1;
          if (special) {
            float s0 = 0.f, s1 = 0.f;
            #pragma unroll
            for (int n = 0; n < 4; ++n) {
              const unsigned j = jw0 + n * 16 + (unsigned)li;
              const bool ip = ispost && (j == i + B_);
              if (ip) posl[i] = 2.0f * acc[m][n][rg];
              if ((j > i) && !ip) {
                float e = __expf(2.0f * acc[m][n][rg]);
                if (j < T) s0 += e; else s1 += e;
              }
            }
            r0 = rsum16(s0); r1 = rsum16(s1);
          } else if ((T > jw0) && (T < jw0 + 64u)) {   // straddle (rare)
            float s0 = 0.f, s1 = 0.f;
            #pragma unroll
            for (int n = 0; n < 4; ++n) {
              const unsigned j = jw0 + n * 16 + (unsigned)li;
              float e = __expf(2.0f * acc[m][n][rg]);
              if (j < T) s0 += e; else s1 += e;
            }
            r0 = rsum16(s0); r1 = rsum16(s1);
          } else {                                      // uniform: 1 reduce
            float sv = 0.f;
            #pragma unroll
            for (int n = 0; n < 4; ++n) sv += __expf(2.0f * acc[m][n][rg]);
            sv = rsum16(sv);
            const bool lo = (T > jw0);
            r0 = lo ? sv : 0.f;
            r1 = lo ? 0.f : sv;
          }
          if (li == 0)
            red2[wc][wr * 64 + m * 16 + hi * 4 + rg] = make_float2(r0, r1);
        }
      }
      // LDS-only wait + raw barrier: does NOT drain the vmcnt prefetch
      asm volatile("s_waitcnt lgkmcnt(0)" ::: "memory");
      __builtin_amdgcn_s_barrier();
      if (t < 128) {
        float2 sm = make_float2(0.f, 0.f);
        #pragma unroll
        for (int w = 0; w < 4; ++w) {
          float2 v = red2[w][t];
          sm.x += v.x; sm.y += v.y;
        }
        part[(size_t)ttb * 128 + t] = sm;
      }
      // reset accumulator for the next tile
      #pragma unroll
      for (int m = 0; m < 4; ++m)
        #pragma unroll
        for (int n = 0; n < 4; ++n) acc[m][n] = (f32x4){0.f, 0.f, 0.f, 0.f};
    }
  }
#undef STAGE
}

// ---------------------------------------------------------------------------
// Kernel C: fused rowreduce + finalize. 64 blocks x 1024 threads; per-block:
// reduce partials for its 128-row panel, bucket-add into global E;
// LAST block (fence+counter, R6-proven) computes the loss.
// ---------------------------------------------------------------------------
__global__ __launch_bounds__(1024) void nt_rowfin(
    const float2* __restrict__ part, const float* __restrict__ posl,
    float* __restrict__ E, unsigned* __restrict__ counter,
    float* __restrict__ out) {
  __shared__ float2 xch[8][128];
  __shared__ int lastflag;
  __shared__ double red[1024];
  const int bi2 = (int)blockIdx.x;             // 0..63 == row panel
  const int t = threadIdx.x;
  const int lrow = t & 127, sh = t >> 7;       // 8 slices per row
  const int base = tile0(bi2);
  const int cnt  = 32 - (bi2 >> 1);

  float2 s = make_float2(0.f, 0.f);
  for (int c = sh; c < cnt; c += 8) {
    float2 v = part[(size_t)(base + c) * 128 + lrow];
    s.x += v.x; s.y += v.y;
  }
  xch[sh][lrow] = s;
  __syncthreads();
  if (t < 128) {
    float sx = 0.f, sy = 0.f;
    #pragma unroll
    for (int w = 0; w < 8; ++w) {
      float2 v = xch[w][t];
      sx += v.x; sy += v.y;
    }
    const unsigned i   = (unsigned)(bi2 * 128 + t);
    const unsigned rlo = rowS(i) / M_;
    atomicAdd(&E[rlo],      sx);
    atomicAdd(&E[rlo + 1u], sy);
  }
  __threadfence();
  __syncthreads();
  if (t == 0) lastflag = (atomicAdd(counter, 1u) == 63u) ? 1 : 0;
  __syncthreads();
  if (!lastflag) return;

  // ---- last block: loss = (1/B) * sum_r ( log(exp(posl)+E[r]) - posl[r] )
  __threadfence();
  double acc = 0.0;
  for (int r = t; r < (int)B_; r += 1024) {
    float ev = atomicAdd(&E[r], 0.0f);      // coherent read (proven)
    float pl = posl[r];
    acc += (double)(logf(__expf(pl) + ev) - pl);
  }
  red[t] = acc;
  __syncthreads();
  for (int m = 512; m > 0; m >>= 1) {
    if (t < m) red[t] += red[t + m];
    __syncthreads();
  }
  if (t == 0) out[0] = (float)(red[0] / (double)B_);
}

// ---------------------------------------------------------------------------
extern "C" void kernel_launch(void* const* d_in, const int* in_sizes, int n_in,
                              void* d_out, int out_size, void* d_ws, size_t ws_size,
                              hipStream_t stream) {
  const float* zis = (const float*)d_in[0];
  const float* zjs = (const float*)d_in[1];
  float* out = (float*)d_out;

  char* ws = (char*)d_ws;
  short*    nb      = (short*)ws;                          // 2 MB
  float*    posl    = (float*)(ws + 2097152);              // 16 KB
  float2*   part    = (float2*)(ws + 2113536);             // 1.08 MB
  float*    E       = (float*)(ws + 3194880);              // 4112 f32
  unsigned* counter = (unsigned*)(ws + 3211328);           // 1 u32
  unsigned* zb      = (unsigned*)E;                        // E+counter contiguous

  nt_norm  <<<dim3(N_ / 8), 256, 0, stream>>>(zis, zjs, nb, zb);
  nt_gemm  <<<dim3(NBLK),   512, 0, stream>>>(nb, part, posl);
  nt_rowfin<<<dim3(64),     1024, 0, stream>>>(part, posl, E, counter, out);
}

// Round 10
// 68.409 us; speedup vs baseline: 1.0423x; 1.0423x over previous
//
#include <hip/hip_runtime.h>
#include <hip/hip_bf16.h>
#include <math.h>

#define B_  4096u
#define N_  8192
#define D_  128
#define M_  8190u          // negatives per logits row = 2B-2
#define SB_ 25159680u      // S_B = B*(2B-2) - B*(B-1)/2
#define NT2_ 1056          // upper-tri 128x256 tiles

#define AS1 __attribute__((address_space(1)))
#define AS3 __attribute__((address_space(3)))

typedef __attribute__((ext_vector_type(8))) short bf16x8;
typedef __attribute__((ext_vector_type(4))) float f32x4;
typedef __attribute__((ext_vector_type(4))) short short4v;

static __device__ __forceinline__ short f2b(float x) {
  __hip_bfloat16 h = __float2bfloat16(x);
  union { __hip_bfloat16 h; short s; } u; u.h = h; return u.s;
}
// cumulative flat-count of strict-upper (minus positives) elements before row i
static __device__ __forceinline__ unsigned rowS(unsigned i) {
  if (i <= B_) return i * (2u * B_ - 2u) - (i * (i - 1u)) / 2u;
  unsigned d = i - B_;
  return SB_ + d * (B_ - 1u) - (d * (d - 1u)) / 2u;
}
// cumulative tile count before row-panel m (128-row panels, 256-col tiles)
static __device__ __forceinline__ int tile0(int m) {
  return 32 * m - (m * m - 2 * m + (m & 1)) / 4;
}
// 16-lane DPP row_ror rotation reduce (validated R7/R8): every lane of each
// 16-group ends with the group sum. VALU-rate, no LDS pipe.
template <int CTRL>
static __device__ __forceinline__ float dpp_add(float x) {
  union { float f; int i; } u, r;
  u.f = x;
  r.i = __builtin_amdgcn_mov_dpp(u.i, CTRL, 0xF, 0xF, 0);
  return x + r.f;
}
static __device__ __forceinline__ float rsum16(float x) {
  x = dpp_add<0x121>(x);   // row_ror:1
  x = dpp_add<0x122>(x);   // row_ror:2
  x = dpp_add<0x124>(x);   // row_ror:4
  x = dpp_add<0x128>(x);   // row_ror:8
  return x;
}

// ---------------------------------------------------------------------------
// Kernel A: normalize rows of reps=[zjs;zis] -> bf16 nb[row][k].
// Block 0 zeroes E buckets + completion counter (replay-safe).
// ---------------------------------------------------------------------------
__global__ __launch_bounds__(256) void nt_norm(
    const float* __restrict__ zis, const float* __restrict__ zjs,
    short* __restrict__ nb, unsigned* __restrict__ zbase) {
  const int t   = threadIdx.x;
  const int row = blockIdx.x * 8 + (t >> 5);
  const int c   = t & 31;
  const float* src = (row < (int)B_) ? (zjs + (size_t)row * D_)
                                     : (zis + (size_t)(row - (int)B_) * D_);
  float4 v = *(const float4*)(src + c * 4);
  float s = v.x * v.x + v.y * v.y + v.z * v.z + v.w * v.w;
  #pragma unroll
  for (int m = 16; m >= 1; m >>= 1) s += __shfl_xor(s, m, 32);
  float rn = 1.0f / fmaxf(sqrtf(s), 1e-8f);
  short4v o;
  o[0] = f2b(v.x * rn); o[1] = f2b(v.y * rn);
  o[2] = f2b(v.z * rn); o[3] = f2b(v.w * rn);
  *(short4v*)(nb + (size_t)row * D_ + c * 4) = o;

  if (blockIdx.x == 0) {
    // E (4112 f32) + counter (1 u32), contiguous
    for (int r = t; r < 4128; r += 256) zbase[r] = 0u;
  }
}

// ---------------------------------------------------------------------------
// Kernel B: 128x256-tile upper-tri Gram, bf16 MFMA, 8 waves (2x4), R8-proven
// pipeline: K=128 as 4 phases of BK=32, 2-buffer LDS via global_load_lds(16B),
// ONE barrier per phase (vmcnt(0) -> s_barrier -> STAGE(ph+1) -> compute).
// s_setprio(1) around the MFMA cluster (T5). Epilogue is register-only:
// inline thresholds, DPP rsum16, per-wave DIRECT global stores — no LDS,
// no barrier, no atomics after the MFMA loop.
// part layout: part[(tile*4 + wc)*128 + row] = (sum_lo, sum_hi)
// ---------------------------------------------------------------------------
__global__ __launch_bounds__(512, 4) void nt_gemm(
    const short* __restrict__ nb, float2* __restrict__ part,
    float* __restrict__ posl) {
  // XCD-chunked bijective swizzle: 1056 = 8 * 132
  const int tb = ((int)blockIdx.x & 7) * 132 + ((int)blockIdx.x >> 3);
  int bi2 = (int)(2.0f * (32.0f - sqrtf(fmaxf(0.f, 1024.0f - (float)tb))));
  if (bi2 > 63) bi2 = 63;
  while (bi2 > 0 && tb < tile0(bi2)) --bi2;
  while (tb >= tile0(bi2 + 1)) ++bi2;
  const int jlo = bi2 >> 1;
  const int bj2 = jlo + (tb - tile0(bi2));

  __shared__ short As[2][128 * 32];     // 2 x 8KB
  __shared__ short Bs[2][256 * 32];     // 2 x 16KB   total 48KB -> 3 blk/CU

  const int t    = threadIdx.x;
  const int lane = t & 63, wave = t >> 6;
  const int li   = lane & 15, hi = lane >> 4;
  const int wr   = wave >> 2, wc = wave & 3;   // 2x4 wave grid
  const int i0   = bi2 * 128, j0 = bj2 * 256;

  const short* gA = nb + (size_t)i0 * D_;
  const short* gB = nb + (size_t)j0 * D_;

#define STAGE(ko, buf) do {                                                   \
    { int e_ = t; int r_ = e_ >> 2, sl_ = e_ & 3, sg_ = sl_ ^ ((r_ >> 1) & 3);\
      __builtin_amdgcn_global_load_lds(                                       \
          (const AS1 void*)(gA + (size_t)r_ * D_ + (ko) + sg_ * 8),           \
          (AS3 void*)(&As[buf][e_ * 8]), 16, 0, 0); }                         \
    _Pragma("unroll")                                                         \
    for (int it_ = 0; it_ < 2; ++it_) {                                       \
      int e_ = it_ * 512 + t;                                                 \
      int r_ = e_ >> 2, sl_ = e_ & 3, sg_ = sl_ ^ ((r_ >> 1) & 3);            \
      __builtin_amdgcn_global_load_lds(                                       \
          (const AS1 void*)(gB + (size_t)r_ * D_ + (ko) + sg_ * 8),           \
          (AS3 void*)(&Bs[buf][e_ * 8]), 16, 0, 0); }                         \
  } while (0)

  STAGE(0, 0);   // prologue: phase 0 into buffer 0

  f32x4 acc[4][4];
  #pragma unroll
  for (int m = 0; m < 4; ++m)
    #pragma unroll
    for (int n = 0; n < 4; ++n) acc[m][n] = (f32x4){0.f, 0.f, 0.f, 0.f};

  const int sw = hi ^ ((li >> 1) & 3);   // swizzled 16B slot for ds_read

  #pragma unroll
  for (int ph = 0; ph < 4; ++ph) {
    // loads for buf (ph&1) were issued a full phase ago -> near-zero wait
    asm volatile("s_waitcnt vmcnt(0)" ::: "memory");
    __builtin_amdgcn_s_barrier();
    __builtin_amdgcn_sched_barrier(0);

    if (ph < 3) STAGE((ph + 1) * 32, (ph + 1) & 1);   // prefetch next phase

    const int cb = ph & 1;
    bf16x8 af[4], bfr[4];
    #pragma unroll
    for (int m = 0; m < 4; ++m)
      af[m] = *(const bf16x8*)(&As[cb][(wr * 64 + m * 16 + li) * 32 + sw * 8]);
    #pragma unroll
    for (int n = 0; n < 4; ++n)
      bfr[n] = *(const bf16x8*)(&Bs[cb][(wc * 64 + n * 16 + li) * 32 + sw * 8]);
    __builtin_amdgcn_s_setprio(1);
    #pragma unroll
    for (int m = 0; m < 4; ++m)
      #pragma unroll
      for (int n = 0; n < 4; ++n)
        acc[m][n] = __builtin_amdgcn_mfma_f32_16x16x32_bf16(
            af[m], bfr[n], acc[m][n], 0, 0, 0);
    __builtin_amdgcn_s_setprio(0);
  }
#undef STAGE

  // ---- epilogue: register-only; per-wave direct global stores ----
  const bool isdiag = (bj2 == jlo);
  const bool ispost = (bj2 == jlo + 16);
  const bool special = isdiag | ispost;
  const unsigned jw0 = (unsigned)(j0 + wc * 64);
  float2* pw = part + ((size_t)tb * 4 + wc) * 128;

  #pragma unroll
  for (int m = 0; m < 4; ++m) {
    #pragma unroll
    for (int rg = 0; rg < 4; ++rg) {
      const int lrow = wr * 64 + m * 16 + hi * 4 + rg;
      const unsigned i = (unsigned)(i0 + lrow);
      const unsigned S = rowS(i);
      unsigned T = (S / M_ + 1u) * M_ - S + i + 1u;   // const-div magic mul
      T += ((i < B_) && (T > i + B_)) ? 1u : 0u;
      float r0, r1;
      if (special) {
        float s0 = 0.f, s1 = 0.f;
        #pragma unroll
        for (int n = 0; n < 4; ++n) {
          const unsigned j = jw0 + n * 16 + (unsigned)li;
          const bool ip = ispost && (j == i + B_);
          if (ip) posl[i] = 2.0f * acc[m][n][rg];
          if ((j > i) && !ip) {
            float e = __expf(2.0f * acc[m][n][rg]);
            if (j < T) s0 += e; else s1 += e;
          }
        }
        r0 = rsum16(s0); r1 = rsum16(s1);
      } else if ((T > jw0) && (T < jw0 + 64u)) {   // straddle (rare)
        float s0 = 0.f, s1 = 0.f;
        #pragma unroll
        for (int n = 0; n < 4; ++n) {
          const unsigned j = jw0 + n * 16 + (unsigned)li;
          float e = __expf(2.0f * acc[m][n][rg]);
          if (j < T) s0 += e; else s1 += e;
        }
        r0 = rsum16(s0); r1 = rsum16(s1);
      } else {                                      // uniform bucket: 1 reduce
        float s = 0.f;
        #pragma unroll
        for (int n = 0; n < 4; ++n) s += __expf(2.0f * acc[m][n][rg]);
        s = rsum16(s);
        const bool lo = (T > jw0);
        r0 = lo ? s : 0.f;
        r1 = lo ? 0.f : s;
      }
      if (li == 0) pw[lrow] = make_float2(r0, r1);
    }
  }
}

// ---------------------------------------------------------------------------
// Kernel C: fused rowreduce + finalize. 64 blocks x 1024 threads; per-block:
// reduce the (tile,wc) partials of its 128-row panel, bucket-add into E;
// LAST block (fence+counter, R6-proven) computes the loss.
// ---------------------------------------------------------------------------
__global__ __launch_bounds__(1024) void nt_rowfin(
    const float2* __restrict__ part, const float* __restrict__ posl,
    float* __restrict__ E, unsigned* __restrict__ counter,
    float* __restrict__ out) {
  __shared__ float2 xch[8][128];
  __shared__ int lastflag;
  __shared__ double red[1024];
  const int bi2 = (int)blockIdx.x;             // 0..63 == row panel
  const int t = threadIdx.x;
  const int lrow = t & 127, sh = t >> 7;       // 8 slices per row
  const int base4 = tile0(bi2) * 4;
  const int nsl   = (32 - (bi2 >> 1)) * 4;     // (tile,wc) slots for this panel

  float2 s = make_float2(0.f, 0.f);
  for (int c = sh; c < nsl; c += 8) {
    float2 v = part[(size_t)(base4 + c) * 128 + lrow];
    s.x += v.x; s.y += v.y;
  }
  xch[sh][lrow] = s;
  __syncthreads();
  if (t < 128) {
    float sx = 0.f, sy = 0.f;
    #pragma unroll
    for (int w = 0; w < 8; ++w) {
      float2 v = xch[w][t];
      sx += v.x; sy += v.y;
    }
    const unsigned i   = (unsigned)(bi2 * 128 + t);
    const unsigned rlo = rowS(i) / M_;
    atomicAdd(&E[rlo],      sx);
    atomicAdd(&E[rlo + 1u], sy);
  }
  __threadfence();
  __syncthreads();
  if (t == 0) lastflag = (atomicAdd(counter, 1u) == 63u) ? 1 : 0;
  __syncthreads();
  if (!lastflag) return;

  // ---- last block: loss = (1/B) * sum_r ( log(exp(posl)+E[r]) - posl[r] )
  __threadfence();
  double acc = 0.0;
  for (int r = t; r < (int)B_; r += 1024) {
    float ev = atomicAdd(&E[r], 0.0f);      // coherent read (proven)
    float pl = posl[r];
    acc += (double)(logf(__expf(pl) + ev) - pl);
  }
  red[t] = acc;
  __syncthreads();
  for (int m = 512; m > 0; m >>= 1) {
    if (t < m) red[t] += red[t + m];
    __syncthreads();
  }
  if (t == 0) out[0] = (float)(red[0] / (double)B_);
}

// ---------------------------------------------------------------------------
extern "C" void kernel_launch(void* const* d_in, const int* in_sizes, int n_in,
                              void* d_out, int out_size, void* d_ws, size_t ws_size,
                              hipStream_t stream) {
  const float* zis = (const float*)d_in[0];
  const float* zjs = (const float*)d_in[1];
  float* out = (float*)d_out;

  char* ws = (char*)d_ws;
  short*    nb      = (short*)ws;                          // 2 MB
  float*    posl    = (float*)(ws + 2097152);              // 16 KB
  float2*   part    = (float2*)(ws + 2113536);             // 1056*4*128*8 = 4.33 MB
  float*    E       = (float*)(ws + 6438912);              // 4112 f32
  unsigned* counter = (unsigned*)(ws + 6455360);           // 1 u32
  unsigned* zb      = (unsigned*)E;                        // E+counter contiguous

  nt_norm  <<<dim3(N_ / 8), 256, 0, stream>>>(zis, zjs, nb, zb);
  nt_gemm  <<<dim3(NT2_),   512, 0, stream>>>(nb, part, posl);
  nt_rowfin<<<dim3(64),     1024, 0, stream>>>(part, posl, E, counter, out);
}

// Round 11
// 61.190 us; speedup vs baseline: 1.1653x; 1.1180x over previous
//
#include <hip/hip_runtime.h>
#include <hip/hip_bf16.h>
#include <math.h>

#define B_  4096u
#define N_  8192
#define D_  128
#define M_  8190u          // negatives per logits row = 2B-2
#define SB_ 25159680u      // S_B = B*(2B-2) - B*(B-1)/2
#define NT2_ 1056          // upper-tri 128x256 tiles

#define AS1 __attribute__((address_space(1)))
#define AS3 __attribute__((address_space(3)))

typedef __attribute__((ext_vector_type(8))) short bf16x8;
typedef __attribute__((ext_vector_type(4))) float f32x4;
typedef __attribute__((ext_vector_type(4))) short short4v;

static __device__ __forceinline__ short f2b(float x) {
  __hip_bfloat16 h = __float2bfloat16(x);
  union { __hip_bfloat16 h; short s; } u; u.h = h; return u.s;
}
// cumulative flat-count of strict-upper (minus positives) elements before row i
static __device__ __forceinline__ unsigned rowS(unsigned i) {
  if (i <= B_) return i * (2u * B_ - 2u) - (i * (i - 1u)) / 2u;
  unsigned d = i - B_;
  return SB_ + d * (B_ - 1u) - (d * (d - 1u)) / 2u;
}
// cumulative tile count before row-panel m (128-row panels, 256-col tiles)
static __device__ __forceinline__ int tile0(int m) {
  return 32 * m - (m * m - 2 * m + (m & 1)) / 4;
}
// 16-lane DPP row_ror rotation reduce (validated R7/R8): every lane of each
// 16-group ends with the group sum. VALU-rate, no LDS pipe.
template <int CTRL>
static __device__ __forceinline__ float dpp_add(float x) {
  union { float f; int i; } u, r;
  u.f = x;
  r.i = __builtin_amdgcn_mov_dpp(u.i, CTRL, 0xF, 0xF, 0);
  return x + r.f;
}
static __device__ __forceinline__ float rsum16(float x) {
  x = dpp_add<0x121>(x);   // row_ror:1
  x = dpp_add<0x122>(x);   // row_ror:2
  x = dpp_add<0x124>(x);   // row_ror:4
  x = dpp_add<0x128>(x);   // row_ror:8
  return x;
}

// ---------------------------------------------------------------------------
// Kernel A: normalize rows of reps=[zjs;zis] -> bf16 nb[row][k]; build Trow;
// block 0 zeroes E buckets + completion counter (replay-safe).
// ---------------------------------------------------------------------------
__global__ __launch_bounds__(256) void nt_norm(
    const float* __restrict__ zis, const float* __restrict__ zjs,
    short* __restrict__ nb, unsigned* __restrict__ Trow,
    unsigned* __restrict__ zbase) {
  const int t   = threadIdx.x;
  const int row = blockIdx.x * 8 + (t >> 5);
  const int c   = t & 31;
  const float* src = (row < (int)B_) ? (zjs + (size_t)row * D_)
                                     : (zis + (size_t)(row - (int)B_) * D_);
  float4 v = *(const float4*)(src + c * 4);
  float s = v.x * v.x + v.y * v.y + v.z * v.z + v.w * v.w;
  #pragma unroll
  for (int m = 16; m >= 1; m >>= 1) s += __shfl_xor(s, m, 32);
  float rn = 1.0f / fmaxf(sqrtf(s), 1e-8f);
  short4v o;
  o[0] = f2b(v.x * rn); o[1] = f2b(v.y * rn);
  o[2] = f2b(v.z * rn); o[3] = f2b(v.w * rn);
  *(short4v*)(nb + (size_t)row * D_ + c * 4) = o;

  if (t < 8) {
    unsigned i   = (unsigned)(blockIdx.x * 8 + t);
    unsigned S   = rowS(i);
    unsigned rlo = S / M_;
    unsigned Sh  = (rlo + 1u) * M_;
    unsigned jt  = Sh - S + i + 1u;
    Trow[i] = jt + ((i < B_ && jt > i + B_) ? 1u : 0u);
  }
  if (blockIdx.x == 0) {
    // E (4112 f32) + counter (1 u32), contiguous
    for (int r = t; r < 4128; r += 256) zbase[r] = 0u;
  }
}

// ---------------------------------------------------------------------------
// Kernel B: 128x256-tile upper-tri Gram, bf16 MFMA, 8 waves (2x4), R8-proven
// pipeline: K=128 as 4 phases of BK=32, 2-buffer LDS via global_load_lds(16B),
// ONE barrier per phase (vmcnt(0) -> s_barrier -> STAGE(ph+1) -> compute).
// LDS is a FLAT 48KB block (manual carve) so the allocator can't pad to 64KB;
// the epilogue red2 buffer ALIASES the As[0] region (provably dead there:
// last As[0] read is phase 2, all global_load_lds drained by phase 3's
// vmcnt(0), cross-wave safety by phase 3's barrier). 48KB -> 3 blocks/CU.
// ---------------------------------------------------------------------------
__global__ __launch_bounds__(512, 4) void nt_gemm(
    const short* __restrict__ nb, const unsigned* __restrict__ Trow,
    float2* __restrict__ part, float* __restrict__ posl) {
  // XCD-chunked bijective swizzle: 1056 = 8 * 132
  const int tb = ((int)blockIdx.x & 7) * 132 + ((int)blockIdx.x >> 3);
  int bi2 = (int)(2.0f * (32.0f - sqrtf(fmaxf(0.f, 1024.0f - (float)tb))));
  if (bi2 > 63) bi2 = 63;
  while (bi2 > 0 && tb < tile0(bi2)) --bi2;
  while (tb >= tile0(bi2 + 1)) ++bi2;
  const int jlo = bi2 >> 1;
  const int bj2 = jlo + (tb - tile0(bi2));

  // flat 48KB: [0,8K)=As0  [8K,16K)=As1  [16K,32K)=Bs0  [32K,48K)=Bs1
  __shared__ float4 smem4[3072];            // 49152 B, 16B-aligned
  char* smem = (char*)smem4;
#define AS_(buf) ((short*)(smem + (buf) * 8192))
#define BS_(buf) ((short*)(smem + 16384 + (buf) * 16384))
  float2* red2 = (float2*)smem;             // aliases As0+As1 (4KB used)

  const int t    = threadIdx.x;
  const int lane = t & 63, wave = t >> 6;
  const int li   = lane & 15, hi = lane >> 4;
  const int wr   = wave >> 2, wc = wave & 3;   // 2x4 wave grid
  const int i0   = bi2 * 128, j0 = bj2 * 256;

  const short* gA = nb + (size_t)i0 * D_;
  const short* gB = nb + (size_t)j0 * D_;

#define STAGE(ko, buf) do {                                                   \
    { int e_ = t; int r_ = e_ >> 2, sl_ = e_ & 3, sg_ = sl_ ^ ((r_ >> 1) & 3);\
      __builtin_amdgcn_global_load_lds(                                       \
          (const AS1 void*)(gA + (size_t)r_ * D_ + (ko) + sg_ * 8),           \
          (AS3 void*)(AS_(buf) + e_ * 8), 16, 0, 0); }                        \
    _Pragma("unroll")                                                         \
    for (int it_ = 0; it_ < 2; ++it_) {                                       \
      int e_ = it_ * 512 + t;                                                 \
      int r_ = e_ >> 2, sl_ = e_ & 3, sg_ = sl_ ^ ((r_ >> 1) & 3);            \
      __builtin_amdgcn_global_load_lds(                                       \
          (const AS1 void*)(gB + (size_t)r_ * D_ + (ko) + sg_ * 8),           \
          (AS3 void*)(BS_(buf) + e_ * 8), 16, 0, 0); }                        \
  } while (0)

  STAGE(0, 0);   // prologue: phase 0 into buffer 0

  f32x4 acc[4][4];
  #pragma unroll
  for (int m = 0; m < 4; ++m)
    #pragma unroll
    for (int n = 0; n < 4; ++n) acc[m][n] = (f32x4){0.f, 0.f, 0.f, 0.f};

  const int sw = hi ^ ((li >> 1) & 3);   // swizzled 16B slot for ds_read

  #pragma unroll
  for (int ph = 0; ph < 4; ++ph) {
    // loads for buf (ph&1) were issued a full phase ago -> near-zero wait
    asm volatile("s_waitcnt vmcnt(0)" ::: "memory");
    __builtin_amdgcn_s_barrier();
    __builtin_amdgcn_sched_barrier(0);

    if (ph < 3) STAGE((ph + 1) * 32, (ph + 1) & 1);   // prefetch next phase

    const int cb = ph & 1;
    bf16x8 af[4], bfr[4];
    #pragma unroll
    for (int m = 0; m < 4; ++m)
      af[m] = *(const bf16x8*)(AS_(cb) + (wr * 64 + m * 16 + li) * 32 + sw * 8);
    #pragma unroll
    for (int n = 0; n < 4; ++n)
      bfr[n] = *(const bf16x8*)(BS_(cb) + (wc * 64 + n * 16 + li) * 32 + sw * 8);
    #pragma unroll
    for (int m = 0; m < 4; ++m)
      #pragma unroll
      for (int n = 0; n < 4; ++n)
        acc[m][n] = __builtin_amdgcn_mfma_f32_16x16x32_bf16(
            af[m], bfr[n], acc[m][n], 0, 0, 0);
  }
#undef STAGE

  // ---- epilogue: bucket sums, DPP reduce, cross-wave combine ----
  // (red2 aliases As0/As1: dead since phase 3's barrier; per-wave rows
  //  disjoint; reads only after __syncthreads below)
  const bool isdiag = (bj2 == jlo);
  const bool ispost = (bj2 == jlo + 16);
  const bool special = isdiag | ispost;
  const unsigned jw0 = (unsigned)(j0 + wc * 64);

  #pragma unroll
  for (int m = 0; m < 4; ++m) {
    const uint4 T4 = *(const uint4*)(Trow + i0 + wr * 64 + m * 16 + hi * 4);
    const unsigned Ts[4] = {T4.x, T4.y, T4.z, T4.w};
    #pragma unroll
    for (int rg = 0; rg < 4; ++rg) {
      const unsigned i = (unsigned)(i0 + wr * 64 + m * 16 + hi * 4 + rg);
      const unsigned T = Ts[rg];
      float r0, r1;
      if (special) {
        float s0 = 0.f, s1 = 0.f;
        #pragma unroll
        for (int n = 0; n < 4; ++n) {
          const unsigned j = jw0 + n * 16 + (unsigned)li;
          const bool ip = ispost && (j == i + B_);
          if (ip) posl[i] = 2.0f * acc[m][n][rg];
          if ((j > i) && !ip) {
            float e = __expf(2.0f * acc[m][n][rg]);
            if (j < T) s0 += e; else s1 += e;
          }
        }
        r0 = rsum16(s0); r1 = rsum16(s1);
      } else if ((T > jw0) && (T < jw0 + 64u)) {   // straddle (rare)
        float s0 = 0.f, s1 = 0.f;
        #pragma unroll
        for (int n = 0; n < 4; ++n) {
          const unsigned j = jw0 + n * 16 + (unsigned)li;
          float e = __expf(2.0f * acc[m][n][rg]);
          if (j < T) s0 += e; else s1 += e;
        }
        r0 = rsum16(s0); r1 = rsum16(s1);
      } else {                                      // uniform bucket: 1 reduce
        float s = 0.f;
        #pragma unroll
        for (int n = 0; n < 4; ++n) s += __expf(2.0f * acc[m][n][rg]);
        s = rsum16(s);
        const bool lo = (T > jw0);
        r0 = lo ? s : 0.f;
        r1 = lo ? 0.f : s;
      }
      if (li == 0)
        red2[wc * 128 + wr * 64 + m * 16 + hi * 4 + rg] = make_float2(r0, r1);
    }
  }
  __syncthreads();

  if (t < 128) {
    float2 s = make_float2(0.f, 0.f);
    #pragma unroll
    for (int w = 0; w < 4; ++w) {
      float2 v = red2[w * 128 + t];
      s.x += v.x; s.y += v.y;
    }
    part[(size_t)tb * 128 + t] = s;
  }
}

// ---------------------------------------------------------------------------
// Kernel C: fused rowreduce + finalize. 64 blocks x 1024 threads; per-block:
// reduce partials for its 128-row panel, bucket-add into global E;
// LAST block (fence+counter, R6-proven) computes the loss.
// ---------------------------------------------------------------------------
__global__ __launch_bounds__(1024) void nt_rowfin(
    const float2* __restrict__ part, const float* __restrict__ posl,
    float* __restrict__ E, unsigned* __restrict__ counter,
    float* __restrict__ out) {
  __shared__ float2 xch[8][128];
  __shared__ int lastflag;
  __shared__ double red[1024];
  const int bi2 = (int)blockIdx.x;             // 0..63 == row panel
  const int t = threadIdx.x;
  const int lrow = t & 127, sh = t >> 7;       // 8 slices per row
  const int base = tile0(bi2);
  const int cnt  = 32 - (bi2 >> 1);

  float2 s = make_float2(0.f, 0.f);
  for (int c = sh; c < cnt; c += 8) {
    float2 v = part[(size_t)(base + c) * 128 + lrow];
    s.x += v.x; s.y += v.y;
  }
  xch[sh][lrow] = s;
  __syncthreads();
  if (t < 128) {
    float sx = 0.f, sy = 0.f;
    #pragma unroll
    for (int w = 0; w < 8; ++w) {
      float2 v = xch[w][t];
      sx += v.x; sy += v.y;
    }
    const unsigned i   = (unsigned)(bi2 * 128 + t);
    const unsigned rlo = rowS(i) / M_;
    atomicAdd(&E[rlo],      sx);
    atomicAdd(&E[rlo + 1u], sy);
  }
  __threadfence();
  __syncthreads();
  if (t == 0) lastflag = (atomicAdd(counter, 1u) == 63u) ? 1 : 0;
  __syncthreads();
  if (!lastflag) return;

  // ---- last block: loss = (1/B) * sum_r ( log(exp(posl)+E[r]) - posl[r] )
  __threadfence();
  double acc = 0.0;
  for (int r = t; r < (int)B_; r += 1024) {
    float ev = atomicAdd(&E[r], 0.0f);      // coherent read (proven)
    float pl = posl[r];
    acc += (double)(logf(__expf(pl) + ev) - pl);
  }
  red[t] = acc;
  __syncthreads();
  for (int m = 512; m > 0; m >>= 1) {
    if (t < m) red[t] += red[t + m];
    __syncthreads();
  }
  if (t == 0) out[0] = (float)(red[0] / (double)B_);
}

// ---------------------------------------------------------------------------
extern "C" void kernel_launch(void* const* d_in, const int* in_sizes, int n_in,
                              void* d_out, int out_size, void* d_ws, size_t ws_size,
                              hipStream_t stream) {
  const float* zis = (const float*)d_in[0];
  const float* zjs = (const float*)d_in[1];
  float* out = (float*)d_out;

  char* ws = (char*)d_ws;
  short*    nb      = (short*)ws;                          // 2 MB
  unsigned* Trow    = (unsigned*)(ws + 2097152);           // 32 KB
  float*    posl    = (float*)(ws + 2129920);              // 16 KB
  float2*   part    = (float2*)(ws + 2146304);             // 1.08 MB
  float*    E       = (float*)(ws + 3227648);              // 4112 f32
  unsigned* counter = (unsigned*)(ws + 3244096);           // 1 u32
  unsigned* zb      = (unsigned*)E;                        // E+counter contiguous

  nt_norm  <<<dim3(N_ / 8), 256, 0, stream>>>(zis, zjs, nb, Trow, zb);
  nt_gemm  <<<dim3(NT2_),   512, 0, stream>>>(nb, Trow, part, posl);
  nt_rowfin<<<dim3(64),     1024, 0, stream>>>(part, posl, E, counter, out);
}

// Round 12
// 53.550 us; speedup vs baseline: 1.3316x; 1.1427x over previous
//
#include <hip/hip_runtime.h>
#include <hip/hip_bf16.h>
#include <math.h>

#define B_  4096u
#define N_  8192
#define D_  128
#define M_  8190u          // negatives per logits row = 2B-2
#define SB_ 25159680u      // S_B = B*(2B-2) - B*(B-1)/2
#define NT2_ 1056          // upper-tri 128x256 tiles

#define AS1 __attribute__((address_space(1)))
#define AS3 __attribute__((address_space(3)))

typedef __attribute__((ext_vector_type(8))) short bf16x8;
typedef __attribute__((ext_vector_type(4))) float f32x4;
typedef __attribute__((ext_vector_type(4))) short short4v;

static __device__ __forceinline__ short f2b(float x) {
  __hip_bfloat16 h = __float2bfloat16(x);
  union { __hip_bfloat16 h; short s; } u; u.h = h; return u.s;
}
// cumulative flat-count of strict-upper (minus positives) elements before row i
static __device__ __forceinline__ unsigned rowS(unsigned i) {
  if (i <= B_) return i * (2u * B_ - 2u) - (i * (i - 1u)) / 2u;
  unsigned d = i - B_;
  return SB_ + d * (B_ - 1u) - (d * (d - 1u)) / 2u;
}
// cumulative tile count before row-panel m (128-row panels, 256-col tiles)
static __device__ __forceinline__ int tile0(int m) {
  return 32 * m - (m * m - 2 * m + (m & 1)) / 4;
}
// 16-lane DPP row_ror rotation reduce (validated R7/R8): every lane of each
// 16-group ends with the group sum. VALU-rate, no LDS pipe.
template <int CTRL>
static __device__ __forceinline__ float dpp_add(float x) {
  union { float f; int i; } u, r;
  u.f = x;
  r.i = __builtin_amdgcn_mov_dpp(u.i, CTRL, 0xF, 0xF, 0);
  return x + r.f;
}
static __device__ __forceinline__ float rsum16(float x) {
  x = dpp_add<0x121>(x);   // row_ror:1
  x = dpp_add<0x122>(x);   // row_ror:2
  x = dpp_add<0x124>(x);   // row_ror:4
  x = dpp_add<0x128>(x);   // row_ror:8
  return x;
}

// ---------------------------------------------------------------------------
// Kernel A: normalize rows of reps=[zjs;zis] -> bf16 nb[row][k]; build Trow;
// block 0 zeroes E buckets + completion counter (replay-safe).
// ---------------------------------------------------------------------------
__global__ __launch_bounds__(256) void nt_norm(
    const float* __restrict__ zis, const float* __restrict__ zjs,
    short* __restrict__ nb, unsigned* __restrict__ Trow,
    unsigned* __restrict__ zbase) {
  const int t   = threadIdx.x;
  const int row = blockIdx.x * 8 + (t >> 5);
  const int c   = t & 31;
  const float* src = (row < (int)B_) ? (zjs + (size_t)row * D_)
                                     : (zis + (size_t)(row - (int)B_) * D_);
  float4 v = *(const float4*)(src + c * 4);
  float s = v.x * v.x + v.y * v.y + v.z * v.z + v.w * v.w;
  #pragma unroll
  for (int m = 16; m >= 1; m >>= 1) s += __shfl_xor(s, m, 32);
  float rn = 1.0f / fmaxf(sqrtf(s), 1e-8f);
  short4v o;
  o[0] = f2b(v.x * rn); o[1] = f2b(v.y * rn);
  o[2] = f2b(v.z * rn); o[3] = f2b(v.w * rn);
  *(short4v*)(nb + (size_t)row * D_ + c * 4) = o;

  if (t < 8) {
    unsigned i   = (unsigned)(blockIdx.x * 8 + t);
    unsigned S   = rowS(i);
    unsigned rlo = S / M_;
    unsigned Sh  = (rlo + 1u) * M_;
    unsigned jt  = Sh - S + i + 1u;
    Trow[i] = jt + ((i < B_ && jt > i + B_) ? 1u : 0u);
  }
  if (blockIdx.x == 0) {
    // E (4112 f32) + counter (1 u32), contiguous
    for (int r = t; r < 4128; r += 256) zbase[r] = 0u;
  }
}

// ---------------------------------------------------------------------------
// Kernel B: 128x256-tile upper-tri Gram, bf16 MFMA, 8 waves (2x4).
// SINGLE DELTA vs R8: K=128 as 4 phases of BK=32 with THREE LDS buffers and
// 2-phase-ahead prefetch + counted vmcnt(3) (never 0 until the last phase).
// Per phase: vmcnt(3) [oldest stage landed] -> s_barrier -> STAGE(ph+2)
// [safe: barrier proves all waves finished phase ph-1 on that buffer] ->
// ds_read + 16 MFMA. Loads get ~2 full phases of latency cover. LDS = 76KB;
// occupancy is VGPR-capped at 2 blocks/CU (acc=64 VGPR), so the extra
// buffer is free. Epilogue identical to R8.
// ---------------------------------------------------------------------------
__global__ __launch_bounds__(512, 4) void nt_gemm(
    const short* __restrict__ nb, const unsigned* __restrict__ Trow,
    float2* __restrict__ part, float* __restrict__ posl) {
  // XCD-chunked bijective swizzle: 1056 = 8 * 132
  const int tb = ((int)blockIdx.x & 7) * 132 + ((int)blockIdx.x >> 3);
  int bi2 = (int)(2.0f * (32.0f - sqrtf(fmaxf(0.f, 1024.0f - (float)tb))));
  if (bi2 > 63) bi2 = 63;
  while (bi2 > 0 && tb < tile0(bi2)) --bi2;
  while (tb >= tile0(bi2 + 1)) ++bi2;
  const int jlo = bi2 >> 1;
  const int bj2 = jlo + (tb - tile0(bi2));

  __shared__ short As[3][128 * 32];     // 3 x 8KB
  __shared__ short Bs[3][256 * 32];     // 3 x 16KB
  __shared__ float2 red2[4][128];       // 4KB          total 76KB

  const int t    = threadIdx.x;
  const int lane = t & 63, wave = t >> 6;
  const int li   = lane & 15, hi = lane >> 4;
  const int wr   = wave >> 2, wc = wave & 3;   // 2x4 wave grid
  const int i0   = bi2 * 128, j0 = bj2 * 256;

  const short* gA = nb + (size_t)i0 * D_;
  const short* gB = nb + (size_t)j0 * D_;

#define STAGE(ko, buf) do {                                                   \
    { int e_ = t; int r_ = e_ >> 2, sl_ = e_ & 3, sg_ = sl_ ^ ((r_ >> 1) & 3);\
      __builtin_amdgcn_global_load_lds(                                       \
          (const AS1 void*)(gA + (size_t)r_ * D_ + (ko) + sg_ * 8),           \
          (AS3 void*)(&As[buf][e_ * 8]), 16, 0, 0); }                         \
    _Pragma("unroll")                                                         \
    for (int it_ = 0; it_ < 2; ++it_) {                                       \
      int e_ = it_ * 512 + t;                                                 \
      int r_ = e_ >> 2, sl_ = e_ & 3, sg_ = sl_ ^ ((r_ >> 1) & 3);            \
      __builtin_amdgcn_global_load_lds(                                       \
          (const AS1 void*)(gB + (size_t)r_ * D_ + (ko) + sg_ * 8),           \
          (AS3 void*)(&Bs[buf][e_ * 8]), 16, 0, 0); }                        \
  } while (0)

  STAGE(0, 0);     // prologue: phase 0 -> buf 0
  STAGE(32, 1);    //           phase 1 -> buf 1

  f32x4 acc[4][4];
  #pragma unroll
  for (int m = 0; m < 4; ++m)
    #pragma unroll
    for (int n = 0; n < 4; ++n) acc[m][n] = (f32x4){0.f, 0.f, 0.f, 0.f};

  const int sw = hi ^ ((li >> 1) & 3);   // swizzled 16B slot for ds_read

  #pragma unroll
  for (int ph = 0; ph < 4; ++ph) {
    // counted wait: oldest outstanding stage (phase ph) has landed;
    // the newer stage(s) stay in flight across the barrier.
    if (ph < 3) asm volatile("s_waitcnt vmcnt(3)" ::: "memory");
    else        asm volatile("s_waitcnt vmcnt(0)" ::: "memory");
    __builtin_amdgcn_s_barrier();
    __builtin_amdgcn_sched_barrier(0);

    if (ph < 2) STAGE((ph + 2) * 32, (ph + 2) % 3);   // 2-ahead prefetch

    const int cb = ph % 3;
    bf16x8 af[4], bfr[4];
    #pragma unroll
    for (int m = 0; m < 4; ++m)
      af[m] = *(const bf16x8*)(&As[cb][(wr * 64 + m * 16 + li) * 32 + sw * 8]);
    #pragma unroll
    for (int n = 0; n < 4; ++n)
      bfr[n] = *(const bf16x8*)(&Bs[cb][(wc * 64 + n * 16 + li) * 32 + sw * 8]);
    #pragma unroll
    for (int m = 0; m < 4; ++m)
      #pragma unroll
      for (int n = 0; n < 4; ++n)
        acc[m][n] = __builtin_amdgcn_mfma_f32_16x16x32_bf16(
            af[m], bfr[n], acc[m][n], 0, 0, 0);
  }
#undef STAGE

  // ---- epilogue: bucket sums, DPP reduce, cross-wave combine (R8) ----
  const bool isdiag = (bj2 == jlo);
  const bool ispost = (bj2 == jlo + 16);
  const bool special = isdiag | ispost;
  const unsigned jw0 = (unsigned)(j0 + wc * 64);

  #pragma unroll
  for (int m = 0; m < 4; ++m) {
    const uint4 T4 = *(const uint4*)(Trow + i0 + wr * 64 + m * 16 + hi * 4);
    const unsigned Ts[4] = {T4.x, T4.y, T4.z, T4.w};
    #pragma unroll
    for (int rg = 0; rg < 4; ++rg) {
      const unsigned i = (unsigned)(i0 + wr * 64 + m * 16 + hi * 4 + rg);
      const unsigned T = Ts[rg];
      float r0, r1;
      if (special) {
        float s0 = 0.f, s1 = 0.f;
        #pragma unroll
        for (int n = 0; n < 4; ++n) {
          const unsigned j = jw0 + n * 16 + (unsigned)li;
          const bool ip = ispost && (j == i + B_);
          if (ip) posl[i] = 2.0f * acc[m][n][rg];
          if ((j > i) && !ip) {
            float e = __expf(2.0f * acc[m][n][rg]);
            if (j < T) s0 += e; else s1 += e;
          }
        }
        r0 = rsum16(s0); r1 = rsum16(s1);
      } else if ((T > jw0) && (T < jw0 + 64u)) {   // straddle (rare)
        float s0 = 0.f, s1 = 0.f;
        #pragma unroll
        for (int n = 0; n < 4; ++n) {
          const unsigned j = jw0 + n * 16 + (unsigned)li;
          float e = __expf(2.0f * acc[m][n][rg]);
          if (j < T) s0 += e; else s1 += e;
        }
        r0 = rsum16(s0); r1 = rsum16(s1);
      } else {                                      // uniform bucket: 1 reduce
        float s = 0.f;
        #pragma unroll
        for (int n = 0; n < 4; ++n) s += __expf(2.0f * acc[m][n][rg]);
        s = rsum16(s);
        const bool lo = (T > jw0);
        r0 = lo ? s : 0.f;
        r1 = lo ? 0.f : s;
      }
      if (li == 0)
        red2[wc][wr * 64 + m * 16 + hi * 4 + rg] = make_float2(r0, r1);
    }
  }
  __syncthreads();

  if (t < 128) {
    float2 s = make_float2(0.f, 0.f);
    #pragma unroll
    for (int w = 0; w < 4; ++w) {
      float2 v = red2[w][t];
      s.x += v.x; s.y += v.y;
    }
    part[(size_t)tb * 128 + t] = s;
  }
}

// ---------------------------------------------------------------------------
// Kernel C: fused rowreduce + finalize (R8-proven, 256 threads). 64 blocks;
// per-block: reduce partials for its 128-row panel, bucket-add into E;
// LAST block (fence+counter) computes the loss.
// ---------------------------------------------------------------------------
__global__ __launch_bounds__(256) void nt_rowfin(
    const float2* __restrict__ part, const float* __restrict__ posl,
    float* __restrict__ E, unsigned* __restrict__ counter,
    float* __restrict__ out) {
  __shared__ float2 xch[128];
  __shared__ int lastflag;
  __shared__ double red[256];
  const int bi2 = (int)blockIdx.x;             // 0..63 == row panel
  const int t = threadIdx.x;
  const int lrow = t & 127, sh = t >> 7;
  const int base = tile0(bi2);
  const int cnt  = 32 - (bi2 >> 1);

  float2 s = make_float2(0.f, 0.f);
  for (int c = sh; c < cnt; c += 2) {
    float2 v = part[(size_t)(base + c) * 128 + lrow];
    s.x += v.x; s.y += v.y;
  }
  if (sh == 1) xch[lrow] = s;
  __syncthreads();
  if (sh == 0) {
    float2 v = xch[lrow];
    s.x += v.x; s.y += v.y;
    const unsigned i   = (unsigned)(bi2 * 128 + lrow);
    const unsigned rlo = rowS(i) / M_;
    atomicAdd(&E[rlo],      s.x);
    atomicAdd(&E[rlo + 1u], s.y);
  }
  __threadfence();
  __syncthreads();
  if (t == 0) lastflag = (atomicAdd(counter, 1u) == 63u) ? 1 : 0;
  __syncthreads();
  if (!lastflag) return;

  // ---- last block: loss = (1/B) * sum_r ( log(exp(posl)+E[r]) - posl[r] )
  __threadfence();
  double acc = 0.0;
  for (int r = t; r < (int)B_; r += 256) {
    float ev = atomicAdd(&E[r], 0.0f);      // coherent read (proven)
    float pl = posl[r];
    acc += (double)(logf(__expf(pl) + ev) - pl);
  }
  red[t] = acc;
  __syncthreads();
  for (int m = 128; m > 0; m >>= 1) {
    if (t < m) red[t] += red[t + m];
    __syncthreads();
  }
  if (t == 0) out[0] = (float)(red[0] / (double)B_);
}

// ---------------------------------------------------------------------------
extern "C" void kernel_launch(void* const* d_in, const int* in_sizes, int n_in,
                              void* d_out, int out_size, void* d_ws, size_t ws_size,
                              hipStream_t stream) {
  const float* zis = (const float*)d_in[0];
  const float* zjs = (const float*)d_in[1];
  float* out = (float*)d_out;

  char* ws = (char*)d_ws;
  short*    nb      = (short*)ws;                          // 2 MB
  unsigned* Trow    = (unsigned*)(ws + 2097152);           // 32 KB
  float*    posl    = (float*)(ws + 2129920);              // 16 KB
  float2*   part    = (float2*)(ws + 2146304);             // 1.08 MB
  float*    E       = (float*)(ws + 3227648);              // 4112 f32
  unsigned* counter = (unsigned*)(ws + 3244096);           // 1 u32
  unsigned* zb      = (unsigned*)E;                        // E+counter contiguous

  nt_norm  <<<dim3(N_ / 8), 256, 0, stream>>>(zis, zjs, nb, Trow, zb);
  nt_gemm  <<<dim3(NT2_),   512, 0, stream>>>(nb, Trow, part, posl);
  nt_rowfin<<<dim3(64),     256, 0, stream>>>(part, posl, E, counter, out);
}